// Round 13
// baseline (287.374 us; speedup 1.0000x reference)
//
#include <hip/hip_runtime.h>

typedef unsigned short ushort_t;
typedef unsigned int uint_t;
typedef __attribute__((ext_vector_type(8))) short bf16x8;
typedef __attribute__((ext_vector_type(4))) float f32x4;

__device__ inline ushort_t bf16_rne(float f) {
    uint_t u = __float_as_uint(f);
    return (ushort_t)((u + 0x7FFFu + ((u >> 16) & 1u)) >> 16);
}

__device__ inline uint_t pack2(float lo, float hi) {
    return (uint_t)bf16_rne(lo) | ((uint_t)bf16_rne(hi) << 16);
}

__device__ inline void acc8(uint4 v, float* a) {
    a[0] += __uint_as_float(v.x << 16);
    a[1] += __uint_as_float(v.x & 0xFFFF0000u);
    a[2] += __uint_as_float(v.y << 16);
    a[3] += __uint_as_float(v.y & 0xFFFF0000u);
    a[4] += __uint_as_float(v.z << 16);
    a[5] += __uint_as_float(v.z & 0xFFFF0000u);
    a[6] += __uint_as_float(v.w << 16);
    a[7] += __uint_as_float(v.w & 0xFFFF0000u);
}

__device__ inline void set8(uint4 v, float* a) {
    a[0] = __uint_as_float(v.x << 16);
    a[1] = __uint_as_float(v.x & 0xFFFF0000u);
    a[2] = __uint_as_float(v.y << 16);
    a[3] = __uint_as_float(v.y & 0xFFFF0000u);
    a[4] = __uint_as_float(v.z << 16);
    a[5] = __uint_as_float(v.z & 0xFFFF0000u);
    a[6] = __uint_as_float(v.w << 16);
    a[7] = __uint_as_float(v.w & 0xFFFF0000u);
}

// ============ bucketed CSR build, atomic-free global path ============
// bucket = dst>>8. blockhist[b][k]: per edge-block histogram -> rewritten to bases.

#define BSH 8
#define NBMAX 512
#define EPB 4096

// blocks < gE: per-block bucket histogram. blocks >= gE: weight transpose prep.
__global__ __launch_bounds__(256) void k_bhist_prep(const int* __restrict__ dst,
                                                    int* __restrict__ blockhist,
                                                    const float* __restrict__ W1,
                                                    const float* __restrict__ W2,
                                                    ushort_t* __restrict__ Wt1,
                                                    ushort_t* __restrict__ Wt2,
                                                    int E, int nb, int gE) {
    const int b = blockIdx.x;
    const int tid = threadIdx.x;
    if (b >= gE) {
        int idx = (b - gE) * 256 + tid;
        if (idx < 16384) {
            int k = idx >> 7, c = idx & 127;
            Wt1[c * 128 + k] = bf16_rne(W1[idx]);
        } else if (idx < 24576) {
            int j = idx - 16384;
            int k = j >> 6, c = j & 63;
            Wt2[c * 128 + k] = bf16_rne(W2[j]);
        }
        return;
    }
    __shared__ int h[NBMAX];
    for (int i = tid; i < NBMAX; i += 256) h[i] = 0;
    __syncthreads();
    const int e0 = b * EPB;
    for (int i = tid; i < EPB; i += 256) {
        int e = e0 + i;
        if (e < E) atomicAdd(&h[dst[e] >> BSH], 1);
    }
    __syncthreads();
    for (int i = tid; i < nb; i += 256) blockhist[b * NBMAX + i] = h[i];
}

// 1 block, 512 threads: bucket totals -> boff/bend; blockhist -> per-block bases.
__global__ __launch_bounds__(512) void k_bscan2(int* __restrict__ blockhist,
                                                int* __restrict__ boff,
                                                int* __restrict__ bend,
                                                int* __restrict__ rowptr,
                                                int nBlk, int nb, int n, int E) {
    __shared__ int a[NBMAX];
    const int k = threadIdx.x;
    int total = 0;
    if (k < nb)
        for (int b = 0; b < nBlk; b++) total += blockhist[b * NBMAX + k];
    a[k] = total;
    __syncthreads();
    for (int off = 1; off < NBMAX; off <<= 1) {
        int x = (k >= off) ? a[k - off] : 0;
        __syncthreads();
        a[k] += x;
        __syncthreads();
    }
    if (k < nb) {
        int excl = a[k] - total;
        boff[k] = excl;
        bend[k] = excl + total;
        int run = excl;
        for (int b = 0; b < nBlk; b++) {
            int t = blockhist[b * NBMAX + k];
            blockhist[b * NBMAX + k] = run;
            run += t;
        }
    }
    if (k == 0) rowptr[n] = E;  // global sentinel: all edges accounted
}

// one edge pass; bases precomputed, LDS cursors only (no global atomics)
__global__ __launch_bounds__(256) void k_bscatter(const int* __restrict__ src,
                                                  const int* __restrict__ dst,
                                                  const int* __restrict__ blockhist,
                                                  uint_t* __restrict__ pairs, int E, int nb) {
    __shared__ int cur[NBMAX];
    const int tid = threadIdx.x;
    for (int i = tid; i < nb; i += 256) cur[i] = blockhist[blockIdx.x * NBMAX + i];
    __syncthreads();
    const int e0 = blockIdx.x * EPB;
    for (int i = tid; i < EPB; i += 256) {
        int e = e0 + i;
        if (e < E) {
            int s = src[e], d = dst[e];
            int off = atomicAdd(&cur[d >> BSH], 1);
            pairs[off] = (uint_t)s | ((uint_t)(d & 255) << 24);
        }
    }
}

// per-bucket: degree, local scan -> rowptr/dinv, local-cursor csr fill
__global__ __launch_bounds__(256) void k_bcsr(const uint_t* __restrict__ pairs,
                                              const int* __restrict__ boff,
                                              const int* __restrict__ bend,
                                              int* __restrict__ rowptr,
                                              float* __restrict__ dinv,
                                              int* __restrict__ csr, int n) {
    __shared__ int deg[256], sc[256], cur[256];
    const int t = threadIdx.x;
    const int b = blockIdx.x;
    const int beg = boff[b], end = bend[b];
    deg[t] = 0;
    __syncthreads();
    for (int i = beg + t; i < end; i += 256) {
        uint_t p = pairs[i];
        atomicAdd(&deg[p >> 24], 1);
    }
    __syncthreads();
    int dv = deg[t];
    sc[t] = dv;
    __syncthreads();
    for (int off = 1; off < 256; off <<= 1) {
        int x = (t >= off) ? sc[t - off] : 0;
        __syncthreads();
        sc[t] += x;
        __syncthreads();
    }
    int excl = sc[t] - dv;
    cur[t] = excl;
    int d = (b << BSH) + t;
    if (d < n) {
        rowptr[d] = beg + excl;
        dinv[d] = rsqrtf((float)dv + 1.0f);
    }
    __syncthreads();
    for (int i = beg + t; i < end; i += 256) {
        uint_t p = pairs[i];
        int off = atomicAdd(&cur[p >> 24], 1);
        csr[beg + off] = (int)(p & 0xFFFFFFu);
    }
}

// --------- MFMA GEMM: G[i][c] = bf16(dinv[i] * sum_k X[i][k]*W[k][c]) ---------

template <int DOUT, bool IN_BF16>
__global__ __launch_bounds__(256) void k_gemm_mfma(const void* __restrict__ Xv,
                                                   const ushort_t* __restrict__ Wt,
                                                   const float* __restrict__ dinv,
                                                   ushort_t* __restrict__ G, int n) {
    constexpr int KP = 136;
    constexpr int NW = DOUT / 2;
    constexpr int NT = NW / 16;
    __shared__ ushort_t Xs[128 * KP];
    __shared__ ushort_t Ws[DOUT * KP];

    const int tid = threadIdx.x;
    const int row0 = blockIdx.x * 128;

    if (!IN_BF16) {
        const float* X = (const float*)Xv;
#pragma unroll
        for (int i = 0; i < 16; i++) {
            int idx = tid * 4 + i * 1024;
            int r = idx >> 7, k = idx & 127;
            int gr = row0 + r;
            float4 v = make_float4(0.f, 0.f, 0.f, 0.f);
            if (gr < n) v = *(const float4*)&X[(size_t)gr * 128 + k];
            ushort4 o;
            o.x = bf16_rne(v.x); o.y = bf16_rne(v.y);
            o.z = bf16_rne(v.z); o.w = bf16_rne(v.w);
            *(ushort4*)&Xs[r * KP + k] = o;
        }
    } else {
        const ushort_t* X = (const ushort_t*)Xv;
#pragma unroll
        for (int i = 0; i < 8; i++) {
            int idx = tid * 8 + i * 2048;
            int r = idx >> 7, k = idx & 127;
            int gr = row0 + r;
            uint4 v = make_uint4(0u, 0u, 0u, 0u);
            if (gr < n) v = *(const uint4*)&X[(size_t)gr * 128 + k];
            *(uint4*)&Xs[r * KP + k] = v;
        }
    }
    constexpr int WI = (DOUT * 128) / 2048;
#pragma unroll
    for (int i = 0; i < WI; i++) {
        int idx = tid * 8 + i * 2048;
        int r = idx >> 7, k = idx & 127;
        *(uint4*)&Ws[r * KP + k] = *(const uint4*)&Wt[idx];
    }
    __syncthreads();

    const int lane = tid & 63;
    const int wid = tid >> 6;
    const int wm = wid & 1, wn = wid >> 1;
    const int lr = lane & 15, kg = lane >> 4;

    f32x4 acc[4][NT];
#pragma unroll
    for (int mi = 0; mi < 4; mi++)
#pragma unroll
        for (int ni = 0; ni < NT; ni++)
#pragma unroll
            for (int q = 0; q < 4; q++) acc[mi][ni][q] = 0.f;

    const ushort_t* xb = &Xs[(wm * 64 + lr) * KP + kg * 8];
    const ushort_t* wb = &Ws[(wn * NW + lr) * KP + kg * 8];

#pragma unroll
    for (int ks = 0; ks < 4; ks++) {
        bf16x8 a[4], b[NT];
#pragma unroll
        for (int mi = 0; mi < 4; mi++)
            a[mi] = *(const bf16x8*)&xb[mi * 16 * KP + ks * 32];
#pragma unroll
        for (int ni = 0; ni < NT; ni++)
            b[ni] = *(const bf16x8*)&wb[ni * 16 * KP + ks * 32];
#pragma unroll
        for (int mi = 0; mi < 4; mi++)
#pragma unroll
            for (int ni = 0; ni < NT; ni++)
                acc[mi][ni] = __builtin_amdgcn_mfma_f32_16x16x32_bf16(
                    a[mi], b[ni], acc[mi][ni], 0, 0, 0);
    }

#pragma unroll
    for (int mi = 0; mi < 4; mi++) {
        int r0 = row0 + wm * 64 + mi * 16 + kg * 4;
#pragma unroll
        for (int r = 0; r < 4; r++) {
            int gr = r0 + r;
            if (gr < n) {
                float s = dinv[gr];
#pragma unroll
                for (int ni = 0; ni < NT; ni++) {
                    int c = wn * NW + ni * 16 + lr;
                    G[(size_t)gr * DOUT + c] = bf16_rne(s * acc[mi][ni][r]);
                }
            }
        }
    }
}

// ---- layer-1 aggregation: 16 lanes/row x uint4, 8-deep unroll, bf16 H out ----

__global__ __launch_bounds__(256) void k_gather128(const int* __restrict__ rowptr,
                                                   const int* __restrict__ csr,
                                                   const ushort_t* __restrict__ G,
                                                   const float* __restrict__ dinv,
                                                   const float* __restrict__ b,
                                                   ushort_t* __restrict__ H, int n) {
    const int g = blockIdx.x * 16 + (threadIdx.x >> 4);
    const int lane = threadIdx.x & 15;
    const int koff = lane * 8;
    if (g >= n) return;
    const int beg = rowptr[g], end = rowptr[g + 1];

    float a[8];
    set8(*(const uint4*)&G[(size_t)g * 128 + koff], a);  // self term
    int e = beg;
    for (; e + 7 < end; e += 8) {
        int s[8];
#pragma unroll
        for (int j = 0; j < 8; j++) s[j] = csr[e + j];
        uint4 v[8];
#pragma unroll
        for (int j = 0; j < 8; j++)
            v[j] = *(const uint4*)&G[(size_t)s[j] * 128 + koff];
#pragma unroll
        for (int j = 0; j < 8; j++) acc8(v[j], a);
    }
    for (; e + 1 < end; e += 2) {
        int s0 = csr[e], s1 = csr[e + 1];
        uint4 v0 = *(const uint4*)&G[(size_t)s0 * 128 + koff];
        uint4 v1 = *(const uint4*)&G[(size_t)s1 * 128 + koff];
        acc8(v0, a); acc8(v1, a);
    }
    if (e < end) {
        int s0 = csr[e];
        acc8(*(const uint4*)&G[(size_t)s0 * 128 + koff], a);
    }
    const float di = dinv[g];
    float4 bb0 = *(const float4*)&b[koff];
    float4 bb1 = *(const float4*)&b[koff + 4];
    uint4 ov;
    ov.x = pack2(fmaxf(di * a[0] + bb0.x, 0.f), fmaxf(di * a[1] + bb0.y, 0.f));
    ov.y = pack2(fmaxf(di * a[2] + bb0.z, 0.f), fmaxf(di * a[3] + bb0.w, 0.f));
    ov.z = pack2(fmaxf(di * a[4] + bb1.x, 0.f), fmaxf(di * a[5] + bb1.y, 0.f));
    ov.w = pack2(fmaxf(di * a[6] + bb1.z, 0.f), fmaxf(di * a[7] + bb1.w, 0.f));
    *(uint4*)&H[(size_t)g * 128 + koff] = ov;
}

// ---- layer-2 aggregation: 8 lanes/row x uint4, 8-deep unroll + mean-pool ----

__global__ __launch_bounds__(256) void k_gather64_pool(const int* __restrict__ rowptr,
                                                       const int* __restrict__ csr,
                                                       const ushort_t* __restrict__ G,
                                                       const float* __restrict__ dinv,
                                                       const float* __restrict__ b,
                                                       const int* __restrict__ batch,
                                                       float* __restrict__ pool, int n) {
    __shared__ float po[32][72];
    __shared__ int pg[32];
    const int grp = threadIdx.x >> 3;
    const int lane = threadIdx.x & 7;
    const int g = blockIdx.x * 32 + grp;
    const int koff = lane * 8;

    float o8[8] = {0.f, 0.f, 0.f, 0.f, 0.f, 0.f, 0.f, 0.f};
    if (g < n) {
        float a[8];
        set8(*(const uint4*)&G[(size_t)g * 64 + koff], a);  // self term
        int e = rowptr[g];
        const int end = rowptr[g + 1];
        for (; e + 7 < end; e += 8) {
            int s[8];
#pragma unroll
            for (int j = 0; j < 8; j++) s[j] = csr[e + j];
            uint4 v[8];
#pragma unroll
            for (int j = 0; j < 8; j++)
                v[j] = *(const uint4*)&G[(size_t)s[j] * 64 + koff];
#pragma unroll
            for (int j = 0; j < 8; j++) acc8(v[j], a);
        }
        for (; e + 1 < end; e += 2) {
            int s0 = csr[e], s1 = csr[e + 1];
            uint4 v0 = *(const uint4*)&G[(size_t)s0 * 64 + koff];
            uint4 v1 = *(const uint4*)&G[(size_t)s1 * 64 + koff];
            acc8(v0, a); acc8(v1, a);
        }
        if (e < end) {
            int s0 = csr[e];
            acc8(*(const uint4*)&G[(size_t)s0 * 64 + koff], a);
        }
        const float di = dinv[g];
        float4 bb0 = *(const float4*)&b[koff];
        float4 bb1 = *(const float4*)&b[koff + 4];
        o8[0] = fmaxf(di * a[0] + bb0.x, 0.f);
        o8[1] = fmaxf(di * a[1] + bb0.y, 0.f);
        o8[2] = fmaxf(di * a[2] + bb0.z, 0.f);
        o8[3] = fmaxf(di * a[3] + bb0.w, 0.f);
        o8[4] = fmaxf(di * a[4] + bb1.x, 0.f);
        o8[5] = fmaxf(di * a[5] + bb1.y, 0.f);
        o8[6] = fmaxf(di * a[6] + bb1.z, 0.f);
        o8[7] = fmaxf(di * a[7] + bb1.w, 0.f);
    }
    if (lane == 0) pg[grp] = (g < n) ? batch[g] : -1;
    *(float4*)&po[grp][koff] = make_float4(o8[0], o8[1], o8[2], o8[3]);
    *(float4*)&po[grp][koff + 4] = make_float4(o8[4], o8[5], o8[6], o8[7]);
    __syncthreads();

    if (threadIdx.x < 64) {
        const int c = threadIdx.x;
        float run = 0.f;
        int cur = -1;
        for (int r = 0; r < 32; r++) {
            int gr = pg[r];
            if (gr < 0) continue;
            if (gr != cur) {
                if (cur >= 0) atomicAdd(&pool[cur * 64 + c], run);
                cur = gr;
                run = 0.f;
            }
            run += po[r][c];
        }
        if (cur >= 0) atomicAdd(&pool[cur * 64 + c], run);
    }
}

// -------------------- pooling tail --------------------

__global__ __launch_bounds__(64) void k_div_bs(const float* __restrict__ pool,
                                               const int* __restrict__ batch,
                                               float* __restrict__ out, int n) {
    int t = blockIdx.x * 64 + threadIdx.x;
    int g = t >> 6;
    int lo = 0, hi = n;
    while (lo < hi) { int m = (lo + hi) >> 1; if (batch[m] < g) lo = m + 1; else hi = m; }
    int lb = lo;
    lo = lb; hi = n;
    while (lo < hi) { int m = (lo + hi) >> 1; if (batch[m] <= g) lo = m + 1; else hi = m; }
    float c = (float)(lo - lb);
    c = c > 1.f ? c : 1.f;
    out[t] = pool[t] / c;
}

// -------------------- launch --------------------

extern "C" void kernel_launch(void* const* d_in, const int* in_sizes, int n_in,
                              void* d_out, int out_size, void* d_ws, size_t ws_size,
                              hipStream_t stream) {
    const float* x = (const float*)d_in[0];
    const int* edge = (const int*)d_in[1];
    const int* batch = (const int*)d_in[2];
    const float* W1 = (const float*)d_in[3];
    const float* b1 = (const float*)d_in[4];
    const float* W2 = (const float*)d_in[5];
    const float* b2 = (const float*)d_in[6];

    const int n = in_sizes[0] / 128;
    const int E = in_sizes[1] / 2;
    const int* src = edge;
    const int* dst = edge + E;
    const int nb = (n + 255) >> BSH;
    const int gE = (E + EPB - 1) / EPB;

    size_t nA = ((size_t)n + 256) & ~(size_t)255;   // n+1 fits (rowptr sentinel)
    float* dinv = (float*)d_ws;                      // nA
    int* rowptr = (int*)(dinv + nA);                 // nA (incl rowptr[n])
    int* boff = rowptr + nA;                         // 512
    int* bend = boff + NBMAX;                        // 512
    float* pool = (float*)(bend + NBMAX);            // 4096 + 256 pad
    ushort_t* Wt1 = (ushort_t*)(pool + 4096 + 256);  // 16384 bf16
    ushort_t* Wt2 = Wt1 + 16384;                     // 8192 bf16
    ushort_t* bufG = Wt2 + 8192;                     // n*128 bf16 (pairs+hist alias)
    ushort_t* bufH = bufG + (size_t)n * 128;         // n*128 bf16
    int* csr = (int*)(bufH + (size_t)n * 128);       // E
    uint_t* pairs = (uint_t*)bufG;                   // E u32 (dead before gemm1)
    int* blockhist = (int*)(pairs + E);              // gE*512 (dead before gemm1)

    hipMemsetAsync(pool, 0, 4096 * 4, stream);

    // CSR build (atomic-free global path) + weight prep fused
    k_bhist_prep<<<gE + 96, 256, 0, stream>>>(dst, blockhist, W1, W2, Wt1, Wt2,
                                              E, nb, gE);
    k_bscan2<<<1, NBMAX, 0, stream>>>(blockhist, boff, bend, rowptr, gE, nb, n, E);
    k_bscatter<<<gE, 256, 0, stream>>>(src, dst, blockhist, pairs, E, nb);
    k_bcsr<<<nb, 256, 0, stream>>>(pairs, boff, bend, rowptr, dinv, csr, n);

    // layer 1: MFMA GEMM (f32 in, bf16 out) -> gather (bf16 H out)
    k_gemm_mfma<128, false><<<(n + 127) / 128, 256, 0, stream>>>(x, Wt1, dinv, bufG, n);
    k_gather128<<<(n + 15) / 16, 256, 0, stream>>>(rowptr, csr, bufG, dinv, b1, bufH, n);

    // layer 2: MFMA GEMM (bf16 in, bf16 out) -> gather + pool
    k_gemm_mfma<64, true><<<(n + 127) / 128, 256, 0, stream>>>(bufH, Wt2, dinv, bufG, n);
    k_gather64_pool<<<(n + 31) / 32, 256, 0, stream>>>(rowptr, csr, bufG, dinv, b2,
                                                       batch, pool, n);

    k_div_bs<<<64, 64, 0, stream>>>(pool, batch, (float*)d_out, n);
}

// Round 14
// 198.736 us; speedup vs baseline: 1.4460x; 1.4460x over previous
//
#include <hip/hip_runtime.h>

typedef unsigned short ushort_t;
typedef unsigned int uint_t;
typedef __attribute__((ext_vector_type(8))) short bf16x8;
typedef __attribute__((ext_vector_type(4))) float f32x4;

__device__ inline ushort_t bf16_rne(float f) {
    uint_t u = __float_as_uint(f);
    return (ushort_t)((u + 0x7FFFu + ((u >> 16) & 1u)) >> 16);
}

__device__ inline uint_t pack2(float lo, float hi) {
    return (uint_t)bf16_rne(lo) | ((uint_t)bf16_rne(hi) << 16);
}

__device__ inline void acc8(uint4 v, float* a) {
    a[0] += __uint_as_float(v.x << 16);
    a[1] += __uint_as_float(v.x & 0xFFFF0000u);
    a[2] += __uint_as_float(v.y << 16);
    a[3] += __uint_as_float(v.y & 0xFFFF0000u);
    a[4] += __uint_as_float(v.z << 16);
    a[5] += __uint_as_float(v.z & 0xFFFF0000u);
    a[6] += __uint_as_float(v.w << 16);
    a[7] += __uint_as_float(v.w & 0xFFFF0000u);
}

__device__ inline void set8(uint4 v, float* a) {
    a[0] = __uint_as_float(v.x << 16);
    a[1] = __uint_as_float(v.x & 0xFFFF0000u);
    a[2] = __uint_as_float(v.y << 16);
    a[3] = __uint_as_float(v.y & 0xFFFF0000u);
    a[4] = __uint_as_float(v.z << 16);
    a[5] = __uint_as_float(v.z & 0xFFFF0000u);
    a[6] = __uint_as_float(v.w << 16);
    a[7] = __uint_as_float(v.w & 0xFFFF0000u);
}

// ============ bucketed CSR build ============
// bucket = dst>>8. blockhist[b][k] -> per-(block,bucket) exclusive prefix (over b).

#define BSH 8
#define NBMAX 512
#define EPB 4096

// blocks < gE: per-block bucket histogram. blocks >= gE: weight transpose prep.
__global__ __launch_bounds__(256) void k_bhist_prep(const int* __restrict__ dst,
                                                    int* __restrict__ blockhist,
                                                    const float* __restrict__ W1,
                                                    const float* __restrict__ W2,
                                                    ushort_t* __restrict__ Wt1,
                                                    ushort_t* __restrict__ Wt2,
                                                    int E, int nb, int gE) {
    const int b = blockIdx.x;
    const int tid = threadIdx.x;
    if (b >= gE) {
        int idx = (b - gE) * 256 + tid;
        if (idx < 16384) {
            int k = idx >> 7, c = idx & 127;
            Wt1[c * 128 + k] = bf16_rne(W1[idx]);
        } else if (idx < 24576) {
            int j = idx - 16384;
            int k = j >> 6, c = j & 63;
            Wt2[c * 128 + k] = bf16_rne(W2[j]);
        }
        return;
    }
    __shared__ int h[NBMAX];
    for (int i = tid; i < NBMAX; i += 256) h[i] = 0;
    __syncthreads();
    const int e0 = b * EPB;
    for (int i = tid; i < EPB; i += 256) {
        int e = e0 + i;
        if (e < E) atomicAdd(&h[dst[e] >> BSH], 1);
    }
    __syncthreads();
    for (int i = tid; i < nb; i += 256) blockhist[b * NBMAX + i] = h[i];
}

// one block PER BUCKET: exclusive scan of blockhist[*][k] over blocks; total -> btot[k]
__global__ __launch_bounds__(512) void k_bscan_bkt(int* __restrict__ blockhist,
                                                   int* __restrict__ btot, int nBlk) {
    __shared__ int a[512];
    const int k = blockIdx.x;
    const int t = threadIdx.x;
    int v = (t < nBlk) ? blockhist[t * NBMAX + k] : 0;
    a[t] = v;
    __syncthreads();
    for (int off = 1; off < 512; off <<= 1) {
        int x = (t >= off) ? a[t - off] : 0;
        __syncthreads();
        a[t] += x;
        __syncthreads();
    }
    if (t < nBlk) blockhist[t * NBMAX + k] = a[t] - v;  // exclusive prefix over blocks
    if (t == 511) btot[k] = a[511];
}

// 1 block: scan bucket totals -> boff/bend; sentinel rowptr[n]=E
__global__ __launch_bounds__(512) void k_bscan_tot(const int* __restrict__ btot,
                                                   int* __restrict__ boff,
                                                   int* __restrict__ bend,
                                                   int* __restrict__ rowptr,
                                                   int nb, int n, int E) {
    __shared__ int a[NBMAX];
    const int k = threadIdx.x;
    int v = (k < nb) ? btot[k] : 0;
    a[k] = v;
    __syncthreads();
    for (int off = 1; off < NBMAX; off <<= 1) {
        int x = (k >= off) ? a[k - off] : 0;
        __syncthreads();
        a[k] += x;
        __syncthreads();
    }
    if (k < nb) {
        int excl = a[k] - v;
        boff[k] = excl;
        bend[k] = excl + v;
    }
    if (k == 0) rowptr[n] = E;
}

// one edge pass; base = blockhist (per-block excl) + boff (bucket offset)
__global__ __launch_bounds__(256) void k_bscatter(const int* __restrict__ src,
                                                  const int* __restrict__ dst,
                                                  const int* __restrict__ blockhist,
                                                  const int* __restrict__ boff,
                                                  uint_t* __restrict__ pairs, int E, int nb) {
    __shared__ int cur[NBMAX];
    const int tid = threadIdx.x;
    for (int i = tid; i < nb; i += 256)
        cur[i] = blockhist[blockIdx.x * NBMAX + i] + boff[i];
    __syncthreads();
    const int e0 = blockIdx.x * EPB;
    for (int i = tid; i < EPB; i += 256) {
        int e = e0 + i;
        if (e < E) {
            int s = src[e], d = dst[e];
            int off = atomicAdd(&cur[d >> BSH], 1);
            pairs[off] = (uint_t)s | ((uint_t)(d & 255) << 24);
        }
    }
}

// per-bucket: degree, local scan -> rowptr/dinv, local-cursor csr fill
__global__ __launch_bounds__(256) void k_bcsr(const uint_t* __restrict__ pairs,
                                              const int* __restrict__ boff,
                                              const int* __restrict__ bend,
                                              int* __restrict__ rowptr,
                                              float* __restrict__ dinv,
                                              int* __restrict__ csr, int n) {
    __shared__ int deg[256], sc[256], cur[256];
    const int t = threadIdx.x;
    const int b = blockIdx.x;
    const int beg = boff[b], end = bend[b];
    deg[t] = 0;
    __syncthreads();
    for (int i = beg + t; i < end; i += 256) {
        uint_t p = pairs[i];
        atomicAdd(&deg[p >> 24], 1);
    }
    __syncthreads();
    int dv = deg[t];
    sc[t] = dv;
    __syncthreads();
    for (int off = 1; off < 256; off <<= 1) {
        int x = (t >= off) ? sc[t - off] : 0;
        __syncthreads();
        sc[t] += x;
        __syncthreads();
    }
    int excl = sc[t] - dv;
    cur[t] = excl;
    int d = (b << BSH) + t;
    if (d < n) {
        rowptr[d] = beg + excl;
        dinv[d] = rsqrtf((float)dv + 1.0f);
    }
    __syncthreads();
    for (int i = beg + t; i < end; i += 256) {
        uint_t p = pairs[i];
        int off = atomicAdd(&cur[p >> 24], 1);
        csr[beg + off] = (int)(p & 0xFFFFFFu);
    }
}

// --------- MFMA GEMM: G[i][c] = bf16(dinv[i] * sum_k X[i][k]*W[k][c]) ---------

template <int DOUT, bool IN_BF16>
__global__ __launch_bounds__(256) void k_gemm_mfma(const void* __restrict__ Xv,
                                                   const ushort_t* __restrict__ Wt,
                                                   const float* __restrict__ dinv,
                                                   ushort_t* __restrict__ G, int n) {
    constexpr int KP = 136;
    constexpr int NW = DOUT / 2;
    constexpr int NT = NW / 16;
    __shared__ ushort_t Xs[128 * KP];
    __shared__ ushort_t Ws[DOUT * KP];

    const int tid = threadIdx.x;
    const int row0 = blockIdx.x * 128;

    if (!IN_BF16) {
        const float* X = (const float*)Xv;
#pragma unroll
        for (int i = 0; i < 16; i++) {
            int idx = tid * 4 + i * 1024;
            int r = idx >> 7, k = idx & 127;
            int gr = row0 + r;
            float4 v = make_float4(0.f, 0.f, 0.f, 0.f);
            if (gr < n) v = *(const float4*)&X[(size_t)gr * 128 + k];
            ushort4 o;
            o.x = bf16_rne(v.x); o.y = bf16_rne(v.y);
            o.z = bf16_rne(v.z); o.w = bf16_rne(v.w);
            *(ushort4*)&Xs[r * KP + k] = o;
        }
    } else {
        const ushort_t* X = (const ushort_t*)Xv;
#pragma unroll
        for (int i = 0; i < 8; i++) {
            int idx = tid * 8 + i * 2048;
            int r = idx >> 7, k = idx & 127;
            int gr = row0 + r;
            uint4 v = make_uint4(0u, 0u, 0u, 0u);
            if (gr < n) v = *(const uint4*)&X[(size_t)gr * 128 + k];
            *(uint4*)&Xs[r * KP + k] = v;
        }
    }
    constexpr int WI = (DOUT * 128) / 2048;
#pragma unroll
    for (int i = 0; i < WI; i++) {
        int idx = tid * 8 + i * 2048;
        int r = idx >> 7, k = idx & 127;
        *(uint4*)&Ws[r * KP + k] = *(const uint4*)&Wt[idx];
    }
    __syncthreads();

    const int lane = tid & 63;
    const int wid = tid >> 6;
    const int wm = wid & 1, wn = wid >> 1;
    const int lr = lane & 15, kg = lane >> 4;

    f32x4 acc[4][NT];
#pragma unroll
    for (int mi = 0; mi < 4; mi++)
#pragma unroll
        for (int ni = 0; ni < NT; ni++)
#pragma unroll
            for (int q = 0; q < 4; q++) acc[mi][ni][q] = 0.f;

    const ushort_t* xb = &Xs[(wm * 64 + lr) * KP + kg * 8];
    const ushort_t* wb = &Ws[(wn * NW + lr) * KP + kg * 8];

#pragma unroll
    for (int ks = 0; ks < 4; ks++) {
        bf16x8 a[4], b[NT];
#pragma unroll
        for (int mi = 0; mi < 4; mi++)
            a[mi] = *(const bf16x8*)&xb[mi * 16 * KP + ks * 32];
#pragma unroll
        for (int ni = 0; ni < NT; ni++)
            b[ni] = *(const bf16x8*)&wb[ni * 16 * KP + ks * 32];
#pragma unroll
        for (int mi = 0; mi < 4; mi++)
#pragma unroll
            for (int ni = 0; ni < NT; ni++)
                acc[mi][ni] = __builtin_amdgcn_mfma_f32_16x16x32_bf16(
                    a[mi], b[ni], acc[mi][ni], 0, 0, 0);
    }

#pragma unroll
    for (int mi = 0; mi < 4; mi++) {
        int r0 = row0 + wm * 64 + mi * 16 + kg * 4;
#pragma unroll
        for (int r = 0; r < 4; r++) {
            int gr = r0 + r;
            if (gr < n) {
                float s = dinv[gr];
#pragma unroll
                for (int ni = 0; ni < NT; ni++) {
                    int c = wn * NW + ni * 16 + lr;
                    G[(size_t)gr * DOUT + c] = bf16_rne(s * acc[mi][ni][r]);
                }
            }
        }
    }
}

// ---- layer-1 aggregation: 16 lanes/row x uint4, 8-deep unroll, bf16 H out ----

__global__ __launch_bounds__(256) void k_gather128(const int* __restrict__ rowptr,
                                                   const int* __restrict__ csr,
                                                   const ushort_t* __restrict__ G,
                                                   const float* __restrict__ dinv,
                                                   const float* __restrict__ b,
                                                   ushort_t* __restrict__ H, int n) {
    const int g = blockIdx.x * 16 + (threadIdx.x >> 4);
    const int lane = threadIdx.x & 15;
    const int koff = lane * 8;
    if (g >= n) return;
    const int beg = rowptr[g], end = rowptr[g + 1];

    float a[8];
    set8(*(const uint4*)&G[(size_t)g * 128 + koff], a);  // self term
    int e = beg;
    for (; e + 7 < end; e += 8) {
        int s[8];
#pragma unroll
        for (int j = 0; j < 8; j++) s[j] = csr[e + j];
        uint4 v[8];
#pragma unroll
        for (int j = 0; j < 8; j++)
            v[j] = *(const uint4*)&G[(size_t)s[j] * 128 + koff];
#pragma unroll
        for (int j = 0; j < 8; j++) acc8(v[j], a);
    }
    for (; e + 1 < end; e += 2) {
        int s0 = csr[e], s1 = csr[e + 1];
        uint4 v0 = *(const uint4*)&G[(size_t)s0 * 128 + koff];
        uint4 v1 = *(const uint4*)&G[(size_t)s1 * 128 + koff];
        acc8(v0, a); acc8(v1, a);
    }
    if (e < end) {
        int s0 = csr[e];
        acc8(*(const uint4*)&G[(size_t)s0 * 128 + koff], a);
    }
    const float di = dinv[g];
    float4 bb0 = *(const float4*)&b[koff];
    float4 bb1 = *(const float4*)&b[koff + 4];
    uint4 ov;
    ov.x = pack2(fmaxf(di * a[0] + bb0.x, 0.f), fmaxf(di * a[1] + bb0.y, 0.f));
    ov.y = pack2(fmaxf(di * a[2] + bb0.z, 0.f), fmaxf(di * a[3] + bb0.w, 0.f));
    ov.z = pack2(fmaxf(di * a[4] + bb1.x, 0.f), fmaxf(di * a[5] + bb1.y, 0.f));
    ov.w = pack2(fmaxf(di * a[6] + bb1.z, 0.f), fmaxf(di * a[7] + bb1.w, 0.f));
    *(uint4*)&H[(size_t)g * 128 + koff] = ov;
}

// ---- layer-2 aggregation: 8 lanes/row x uint4, 8-deep unroll + mean-pool ----

__global__ __launch_bounds__(256) void k_gather64_pool(const int* __restrict__ rowptr,
                                                       const int* __restrict__ csr,
                                                       const ushort_t* __restrict__ G,
                                                       const float* __restrict__ dinv,
                                                       const float* __restrict__ b,
                                                       const int* __restrict__ batch,
                                                       float* __restrict__ pool, int n) {
    __shared__ float po[32][72];
    __shared__ int pg[32];
    const int grp = threadIdx.x >> 3;
    const int lane = threadIdx.x & 7;
    const int g = blockIdx.x * 32 + grp;
    const int koff = lane * 8;

    float o8[8] = {0.f, 0.f, 0.f, 0.f, 0.f, 0.f, 0.f, 0.f};
    if (g < n) {
        float a[8];
        set8(*(const uint4*)&G[(size_t)g * 64 + koff], a);  // self term
        int e = rowptr[g];
        const int end = rowptr[g + 1];
        for (; e + 7 < end; e += 8) {
            int s[8];
#pragma unroll
            for (int j = 0; j < 8; j++) s[j] = csr[e + j];
            uint4 v[8];
#pragma unroll
            for (int j = 0; j < 8; j++)
                v[j] = *(const uint4*)&G[(size_t)s[j] * 64 + koff];
#pragma unroll
            for (int j = 0; j < 8; j++) acc8(v[j], a);
        }
        for (; e + 1 < end; e += 2) {
            int s0 = csr[e], s1 = csr[e + 1];
            uint4 v0 = *(const uint4*)&G[(size_t)s0 * 64 + koff];
            uint4 v1 = *(const uint4*)&G[(size_t)s1 * 64 + koff];
            acc8(v0, a); acc8(v1, a);
        }
        if (e < end) {
            int s0 = csr[e];
            acc8(*(const uint4*)&G[(size_t)s0 * 64 + koff], a);
        }
        const float di = dinv[g];
        float4 bb0 = *(const float4*)&b[koff];
        float4 bb1 = *(const float4*)&b[koff + 4];
        o8[0] = fmaxf(di * a[0] + bb0.x, 0.f);
        o8[1] = fmaxf(di * a[1] + bb0.y, 0.f);
        o8[2] = fmaxf(di * a[2] + bb0.z, 0.f);
        o8[3] = fmaxf(di * a[3] + bb0.w, 0.f);
        o8[4] = fmaxf(di * a[4] + bb1.x, 0.f);
        o8[5] = fmaxf(di * a[5] + bb1.y, 0.f);
        o8[6] = fmaxf(di * a[6] + bb1.z, 0.f);
        o8[7] = fmaxf(di * a[7] + bb1.w, 0.f);
    }
    if (lane == 0) pg[grp] = (g < n) ? batch[g] : -1;
    *(float4*)&po[grp][koff] = make_float4(o8[0], o8[1], o8[2], o8[3]);
    *(float4*)&po[grp][koff + 4] = make_float4(o8[4], o8[5], o8[6], o8[7]);
    __syncthreads();

    if (threadIdx.x < 64) {
        const int c = threadIdx.x;
        float run = 0.f;
        int cur = -1;
        for (int r = 0; r < 32; r++) {
            int gr = pg[r];
            if (gr < 0) continue;
            if (gr != cur) {
                if (cur >= 0) atomicAdd(&pool[cur * 64 + c], run);
                cur = gr;
                run = 0.f;
            }
            run += po[r][c];
        }
        if (cur >= 0) atomicAdd(&pool[cur * 64 + c], run);
    }
}

// -------------------- pooling tail --------------------

__global__ __launch_bounds__(64) void k_div_bs(const float* __restrict__ pool,
                                               const int* __restrict__ batch,
                                               float* __restrict__ out, int n) {
    int t = blockIdx.x * 64 + threadIdx.x;
    int g = t >> 6;
    int lo = 0, hi = n;
    while (lo < hi) { int m = (lo + hi) >> 1; if (batch[m] < g) lo = m + 1; else hi = m; }
    int lb = lo;
    lo = lb; hi = n;
    while (lo < hi) { int m = (lo + hi) >> 1; if (batch[m] <= g) lo = m + 1; else hi = m; }
    float c = (float)(lo - lb);
    c = c > 1.f ? c : 1.f;
    out[t] = pool[t] / c;
}

// -------------------- launch --------------------

extern "C" void kernel_launch(void* const* d_in, const int* in_sizes, int n_in,
                              void* d_out, int out_size, void* d_ws, size_t ws_size,
                              hipStream_t stream) {
    const float* x = (const float*)d_in[0];
    const int* edge = (const int*)d_in[1];
    const int* batch = (const int*)d_in[2];
    const float* W1 = (const float*)d_in[3];
    const float* b1 = (const float*)d_in[4];
    const float* W2 = (const float*)d_in[5];
    const float* b2 = (const float*)d_in[6];

    const int n = in_sizes[0] / 128;
    const int E = in_sizes[1] / 2;
    const int* src = edge;
    const int* dst = edge + E;
    const int nb = (n + 255) >> BSH;
    const int gE = (E + EPB - 1) / EPB;

    size_t nA = ((size_t)n + 256) & ~(size_t)255;   // n+1 fits (rowptr sentinel)
    float* dinv = (float*)d_ws;                      // nA
    int* rowptr = (int*)(dinv + nA);                 // nA (incl rowptr[n])
    int* boff = rowptr + nA;                         // 512
    int* bend = boff + NBMAX;                        // 512
    int* btot = bend + NBMAX;                        // 512
    float* pool = (float*)(btot + NBMAX);            // 4096 + 256 pad
    ushort_t* Wt1 = (ushort_t*)(pool + 4096 + 256);  // 16384 bf16
    ushort_t* Wt2 = Wt1 + 16384;                     // 8192 bf16
    ushort_t* bufG = Wt2 + 8192;                     // n*128 bf16 (pairs+hist alias)
    ushort_t* bufH = bufG + (size_t)n * 128;         // n*128 bf16
    int* csr = (int*)(bufH + (size_t)n * 128);       // E
    uint_t* pairs = (uint_t*)bufG;                   // E u32 (dead before gemm1)
    int* blockhist = (int*)(pairs + E);              // gE*512 (dead before gemm1)

    hipMemsetAsync(pool, 0, 4096 * 4, stream);

    // CSR build + fused weight prep
    k_bhist_prep<<<gE + 96, 256, 0, stream>>>(dst, blockhist, W1, W2, Wt1, Wt2,
                                              E, nb, gE);
    k_bscan_bkt<<<nb, 512, 0, stream>>>(blockhist, btot, gE);
    k_bscan_tot<<<1, NBMAX, 0, stream>>>(btot, boff, bend, rowptr, nb, n, E);
    k_bscatter<<<gE, 256, 0, stream>>>(src, dst, blockhist, boff, pairs, E, nb);
    k_bcsr<<<nb, 256, 0, stream>>>(pairs, boff, bend, rowptr, dinv, csr, n);

    // layer 1: MFMA GEMM (f32 in, bf16 out) -> gather (bf16 H out)
    k_gemm_mfma<128, false><<<(n + 127) / 128, 256, 0, stream>>>(x, Wt1, dinv, bufG, n);
    k_gather128<<<(n + 15) / 16, 256, 0, stream>>>(rowptr, csr, bufG, dinv, b1, bufH, n);

    // layer 2: MFMA GEMM (bf16 in, bf16 out) -> gather + pool
    k_gemm_mfma<64, true><<<(n + 127) / 128, 256, 0, stream>>>(bufH, Wt2, dinv, bufG, n);
    k_gather64_pool<<<(n + 31) / 32, 256, 0, stream>>>(rowptr, csr, bufG, dinv, b2,
                                                       batch, pool, n);

    k_div_bs<<<64, 64, 0, stream>>>(pool, batch, (float*)d_out, n);
}